// Round 8
// baseline (377.367 us; speedup 1.0000x reference)
//
#include <hip/hip_runtime.h>

#define DD 128
#define HH 160
#define WW 160
#define PLANE (DD * HH * WW)   // 3276800 voxels

// ---------------------------------------------------------------------------
// Pack: channel-major velocity -> interleaved xyz (12 B/voxel), prescaled by
// 2^-7 (exact power of two; commutes with all later roundings).
// ---------------------------------------------------------------------------
__global__ __launch_bounds__(256) void pack_kernel(const float* __restrict__ vel,
                                                   float* __restrict__ out) {
    int idx = blockIdx.x * blockDim.x + threadIdx.x;
    if (idx >= PLANE) return;
    const float s = 1.0f / 128.0f;
    float vx = __fmul_rn(vel[idx],             s);
    float vy = __fmul_rn(vel[idx + PLANE],     s);
    float vz = __fmul_rn(vel[idx + 2 * PLANE], s);
    float* p = out + idx * 3;
    p[0] = vx; p[1] = vy; p[2] = vz;
}

// ---------------------------------------------------------------------------
// Gather phase for one voxel: compute sample position (exact _rn chain in the
// reference's op order), issue the (exec-masked) corner loads into cv[24],
// and the masked weights into cw[8]. OOB corners have reference-weight
// exactly 0 -> skipping their load is bit-safe.
// ---------------------------------------------------------------------------
__device__ __forceinline__ void gather_phase(const float* __restrict__ fin,
                                             int x, int y, int z, int idx,
                                             float* __restrict__ cv,   // [24]
                                             float* __restrict__ cw,   // [8]
                                             float& fx, float& fy, float& fz) {
    const float* self = fin + idx * 3;
    fx = self[0]; fy = self[1]; fz = self[2];

    // grid = sample_grid + flow*100  (separate mul + add, NO fma)
    float px = __fadd_rn((float)x, __fmul_rn(fx, 100.0f));
    float py = __fadd_rn((float)y, __fmul_rn(fy, 100.0f));
    float pz = __fadd_rn((float)z, __fmul_rn(fz, 100.0f));

    // normalize: (p - ext/2) / ext * 2   (ext = [159, 159, 127])
    float gx = __fmul_rn(__fdiv_rn(__fsub_rn(px, 79.5f), 159.0f), 2.0f);
    float gy = __fmul_rn(__fdiv_rn(__fsub_rn(py, 79.5f), 159.0f), 2.0f);
    float gz = __fmul_rn(__fdiv_rn(__fsub_rn(pz, 63.5f), 127.0f), 2.0f);

    // denormalize: ((g + 1) * 0.5) * (N-1)  — left-associated like the ref
    float ix = __fmul_rn(__fmul_rn(__fadd_rn(gx, 1.0f), 0.5f), 159.0f);
    float iy = __fmul_rn(__fmul_rn(__fadd_rn(gy, 1.0f), 0.5f), 159.0f);
    float iz = __fmul_rn(__fmul_rn(__fadd_rn(gz, 1.0f), 0.5f), 127.0f);

    float x0f = floorf(ix), y0f = floorf(iy), z0f = floorf(iz);
    int x0 = (int)x0f, y0 = (int)y0f, z0 = (int)z0f;

    bool xin[2], yin[2], zin[2];
#pragma unroll
    for (int d = 0; d < 2; ++d) {
        xin[d] = (x0 + d >= 0) && (x0 + d < WW);
        yin[d] = (y0 + d >= 0) && (y0 + d < HH);
        zin[d] = (z0 + d >= 0) && (z0 + d < DD);
    }

    float wx1 = __fsub_rn(ix, x0f);
    float wy1 = __fsub_rn(iy, y0f);
    float wz1 = __fsub_rn(iz, z0f);
    float wxa[2] = { __fsub_rn(1.0f, wx1), wx1 };
    float wya[2] = { __fsub_rn(1.0f, wy1), wy1 };
    float wza[2] = { __fsub_rn(1.0f, wz1), wz1 };

#pragma unroll
    for (int dz = 0; dz < 2; ++dz) {
#pragma unroll
        for (int dy = 0; dy < 2; ++dy) {
#pragma unroll
            for (int dx = 0; dx < 2; ++dx) {
                int c = dz * 4 + dy * 2 + dx;
                bool inb = zin[dz] && yin[dy] && xin[dx];
                float vx = 0.0f, vy = 0.0f, vz = 0.0f;
                if (inb) {
                    const float* p = fin + (((z0 + dz) * HH + (y0 + dy)) * WW + (x0 + dx)) * 3;
                    vx = p[0]; vy = p[1]; vz = p[2];
                }
                cv[c * 3 + 0] = vx;
                cv[c * 3 + 1] = vy;
                cv[c * 3 + 2] = vz;
                float w = __fmul_rn(__fmul_rn(wza[dz], wya[dy]), wxa[dx]);
                cw[c] = inb ? w : 0.0f;
            }
        }
    }
}

__device__ __forceinline__ void combine_phase(const float* __restrict__ cv,
                                              const float* __restrict__ cw,
                                              float fx, float fy, float fz,
                                              float& ox, float& oy, float& oz) {
    float sx = 0.0f, sy = 0.0f, sz = 0.0f;
#pragma unroll
    for (int c = 0; c < 8; ++c) {   // reference corner order: z outer, y, x
        sx = __fadd_rn(sx, __fmul_rn(cv[c * 3 + 0], cw[c]));
        sy = __fadd_rn(sy, __fmul_rn(cv[c * 3 + 1], cw[c]));
        sz = __fadd_rn(sz, __fmul_rn(cv[c * 3 + 2], cw[c]));
    }
    ox = __fadd_rn(fx, sx);
    oy = __fadd_rn(fy, sy);
    oz = __fadd_rn(fz, sz);
}

// ---------------------------------------------------------------------------
// One step, tiled + z-paired: block covers a 16x16x2 voxel brick (256 threads,
// 2 voxels/thread stacked in z). Wave = 16x4x2 brick -> same cache footprint
// as R7's tile (locality preserved) but 2x gather loads in flight per wave
// (both gather phases issue before either combine consumes).
// Per-voxel fp math identical to R7 (bit-exact output).
// ---------------------------------------------------------------------------
template<bool DST_CM>
__global__ __launch_bounds__(256) void diffeo_step(const float* __restrict__ fin,
                                                   float* __restrict__ fout) {
    int tx = threadIdx.x & 15;
    int ty = threadIdx.x >> 4;
    int x = blockIdx.x * 16 + tx;
    int y = blockIdx.y * 16 + ty;
    int z = blockIdx.z * 2;               // voxel A at z, voxel B at z+1
    int idxA = (z * HH + y) * WW + x;
    int idxB = idxA + HH * WW;

    float cvA[24], cwA[8], fxA, fyA, fzA;
    float cvB[24], cwB[8], fxB, fyB, fzB;

    gather_phase(fin, x, y, z,     idxA, cvA, cwA, fxA, fyA, fzA);
    gather_phase(fin, x, y, z + 1, idxB, cvB, cwB, fxB, fyB, fzB);

    float oxA, oyA, ozA, oxB, oyB, ozB;
    combine_phase(cvA, cwA, fxA, fyA, fzA, oxA, oyA, ozA);
    combine_phase(cvB, cwB, fxB, fyB, fzB, oxB, oyB, ozB);

    if (DST_CM) {
        fout[idxA]             = oxA;
        fout[idxA + PLANE]     = oyA;
        fout[idxA + 2 * PLANE] = ozA;
        fout[idxB]             = oxB;
        fout[idxB + PLANE]     = oyB;
        fout[idxB + 2 * PLANE] = ozB;
    } else {
        float* pA = fout + idxA * 3;
        pA[0] = oxA; pA[1] = oyA; pA[2] = ozA;
        float* pB = fout + idxB * 3;
        pB[0] = oxB; pB[1] = oyB; pB[2] = ozB;
    }
}

extern "C" void kernel_launch(void* const* d_in, const int* in_sizes, int n_in,
                              void* d_out, int out_size, void* d_ws, size_t ws_size,
                              hipStream_t stream) {
    const float* velocity = (const float*)d_in[0];
    float* A = (float*)d_out;  // interleaved scratch until the final step
    float* B = (float*)d_ws;   // interleaved scratch

    const int threads = 256;
    const int pack_blocks = (PLANE + threads - 1) / threads;
    dim3 tile_grid(WW / 16, HH / 16, DD / 2);   // (10, 10, 64)

    pack_kernel<<<pack_blocks, threads, 0, stream>>>(velocity, B);

    // s1..s7 ping-pong; s7 reads B, writes d_out channel-major. Never aliased.
    diffeo_step<false><<<tile_grid, threads, 0, stream>>>(B, A);  // s1
    diffeo_step<false><<<tile_grid, threads, 0, stream>>>(A, B);  // s2
    diffeo_step<false><<<tile_grid, threads, 0, stream>>>(B, A);  // s3
    diffeo_step<false><<<tile_grid, threads, 0, stream>>>(A, B);  // s4
    diffeo_step<false><<<tile_grid, threads, 0, stream>>>(B, A);  // s5
    diffeo_step<false><<<tile_grid, threads, 0, stream>>>(A, B);  // s6
    diffeo_step<true ><<<tile_grid, threads, 0, stream>>>(B, A);  // s7 -> d_out
}

// Round 9
// 351.099 us; speedup vs baseline: 1.0748x; 1.0748x over previous
//
#include <hip/hip_runtime.h>

#define DD 128
#define HH 160
#define WW 160
#define PLANE (DD * HH * WW)   // 3276800 voxels

// grid geometry for the step kernel: 16x16 tiles in (x,y), one z-layer each
#define GX 10                  // WW/16
#define GY 10                  // HH/16
#define NWG (GX * GY * DD)     // 12800 blocks, 12800 % 8 == 0
#define QPX (NWG / 8)          // 1600 blocks per XCD

// ---------------------------------------------------------------------------
// Pack: channel-major velocity -> interleaved xyz (12 B/voxel), prescaled by
// 2^-7 (exact power of two; commutes with all later roundings).
// ---------------------------------------------------------------------------
__global__ __launch_bounds__(256) void pack_kernel(const float* __restrict__ vel,
                                                   float* __restrict__ out) {
    int idx = blockIdx.x * blockDim.x + threadIdx.x;
    if (idx >= PLANE) return;
    const float s = 1.0f / 128.0f;
    float vx = __fmul_rn(vel[idx],             s);
    float vy = __fmul_rn(vel[idx + PLANE],     s);
    float vz = __fmul_rn(vel[idx + 2 * PLANE], s);
    float* p = out + idx * 3;
    p[0] = vx; p[1] = vy; p[2] = vz;
}

// ---------------------------------------------------------------------------
// One scaling-and-squaring step, 12 B interleaved flow, tiled 16x16x1 blocks
// with XCD-AWARE BIJECTIVE SWIZZLE: consecutive blockIdx round-robin across
// the 8 XCDs (each with a private 4 MB L2), so remap id -> (id&7)*QPX+(id>>3):
// XCD k then owns a contiguous 16-layer z-slab, and its concurrently-active
// blocks span ~2 z-layers + gather halo -> gather misses hit the LOCAL L2
// (~200 cyc) instead of L3/peer-L2 (~600 cyc). Pure scheduling change;
// per-voxel fp math identical to R7 (bit-exact output).
//
// OOB corners (reference weight exactly 0) are skipped via exec-masked loads
// (bit-safe). All fp ops use _rn intrinsics in the reference's exact order.
// ---------------------------------------------------------------------------
template<bool DST_CM>
__global__ __launch_bounds__(256) void diffeo_step(const float* __restrict__ fin,
                                                   float* __restrict__ fout) {
    // bijective XCD swizzle (NWG % 8 == 0)
    int nid = (blockIdx.x & 7) * QPX + (blockIdx.x >> 3);
    int bx = nid % GX;
    int by = (nid / GX) % GY;
    int bz = nid / (GX * GY);

    int tx = threadIdx.x & 15;
    int ty = threadIdx.x >> 4;
    int x = bx * 16 + tx;
    int y = by * 16 + ty;
    int z = bz;
    int idx = (z * HH + y) * WW + x;

    const float* self = fin + idx * 3;
    float fx = self[0];
    float fy = self[1];
    float fz = self[2];

    // grid = sample_grid + flow*100  (separate mul + add, NO fma)
    float px = __fadd_rn((float)x, __fmul_rn(fx, 100.0f));
    float py = __fadd_rn((float)y, __fmul_rn(fy, 100.0f));
    float pz = __fadd_rn((float)z, __fmul_rn(fz, 100.0f));

    // normalize: (p - ext/2) / ext * 2   (ext = [159, 159, 127])
    float gx = __fmul_rn(__fdiv_rn(__fsub_rn(px, 79.5f), 159.0f), 2.0f);
    float gy = __fmul_rn(__fdiv_rn(__fsub_rn(py, 79.5f), 159.0f), 2.0f);
    float gz = __fmul_rn(__fdiv_rn(__fsub_rn(pz, 63.5f), 127.0f), 2.0f);

    // denormalize: ((g + 1) * 0.5) * (N-1)  — left-associated like the ref
    float ix = __fmul_rn(__fmul_rn(__fadd_rn(gx, 1.0f), 0.5f), 159.0f);
    float iy = __fmul_rn(__fmul_rn(__fadd_rn(gy, 1.0f), 0.5f), 159.0f);
    float iz = __fmul_rn(__fmul_rn(__fadd_rn(gz, 1.0f), 0.5f), 127.0f);

    float x0f = floorf(ix), y0f = floorf(iy), z0f = floorf(iz);
    int x0 = (int)x0f, y0 = (int)y0f, z0 = (int)z0f;

    bool xin[2], yin[2], zin[2];
#pragma unroll
    for (int d = 0; d < 2; ++d) {
        xin[d] = (x0 + d >= 0) && (x0 + d < WW);
        yin[d] = (y0 + d >= 0) && (y0 + d < HH);
        zin[d] = (z0 + d >= 0) && (z0 + d < DD);
    }

    float wx1 = __fsub_rn(ix, x0f);
    float wy1 = __fsub_rn(iy, y0f);
    float wz1 = __fsub_rn(iz, z0f);
    float wxa[2] = { __fsub_rn(1.0f, wx1), wx1 };
    float wya[2] = { __fsub_rn(1.0f, wy1), wy1 };
    float wza[2] = { __fsub_rn(1.0f, wz1), wz1 };

    // Exec-masked corner gathers; accumulate afterwards in the reference's
    // corner order (z outer, y mid, x inner).
    float cv[24];
    float cw[8];
#pragma unroll
    for (int dz = 0; dz < 2; ++dz) {
#pragma unroll
        for (int dy = 0; dy < 2; ++dy) {
#pragma unroll
            for (int dx = 0; dx < 2; ++dx) {
                int c = dz * 4 + dy * 2 + dx;
                bool inb = zin[dz] && yin[dy] && xin[dx];
                float vx = 0.0f, vy = 0.0f, vz = 0.0f;
                if (inb) {
                    const float* p = fin + (((z0 + dz) * HH + (y0 + dy)) * WW + (x0 + dx)) * 3;
                    vx = p[0]; vy = p[1]; vz = p[2];
                }
                cv[c * 3 + 0] = vx;
                cv[c * 3 + 1] = vy;
                cv[c * 3 + 2] = vz;
                float w = __fmul_rn(__fmul_rn(wza[dz], wya[dy]), wxa[dx]);
                cw[c] = inb ? w : 0.0f;
            }
        }
    }

    float sx = 0.0f, sy = 0.0f, sz = 0.0f;
#pragma unroll
    for (int c = 0; c < 8; ++c) {
        sx = __fadd_rn(sx, __fmul_rn(cv[c * 3 + 0], cw[c]));
        sy = __fadd_rn(sy, __fmul_rn(cv[c * 3 + 1], cw[c]));
        sz = __fadd_rn(sz, __fmul_rn(cv[c * 3 + 2], cw[c]));
    }

    float ox = __fadd_rn(fx, sx);
    float oy = __fadd_rn(fy, sy);
    float oz = __fadd_rn(fz, sz);

    if (DST_CM) {
        fout[idx]             = ox;
        fout[idx + PLANE]     = oy;
        fout[idx + 2 * PLANE] = oz;
    } else {
        float* p = fout + idx * 3;
        p[0] = ox; p[1] = oy; p[2] = oz;
    }
}

extern "C" void kernel_launch(void* const* d_in, const int* in_sizes, int n_in,
                              void* d_out, int out_size, void* d_ws, size_t ws_size,
                              hipStream_t stream) {
    const float* velocity = (const float*)d_in[0];
    float* A = (float*)d_out;  // interleaved scratch until the final step
    float* B = (float*)d_ws;   // interleaved scratch

    const int threads = 256;
    const int pack_blocks = (PLANE + threads - 1) / threads;

    pack_kernel<<<pack_blocks, threads, 0, stream>>>(velocity, B);

    // s1..s7 ping-pong; s7 reads B, writes d_out channel-major. Never aliased.
    diffeo_step<false><<<NWG, threads, 0, stream>>>(B, A);  // s1
    diffeo_step<false><<<NWG, threads, 0, stream>>>(A, B);  // s2
    diffeo_step<false><<<NWG, threads, 0, stream>>>(B, A);  // s3
    diffeo_step<false><<<NWG, threads, 0, stream>>>(A, B);  // s4
    diffeo_step<false><<<NWG, threads, 0, stream>>>(B, A);  // s5
    diffeo_step<false><<<NWG, threads, 0, stream>>>(A, B);  // s6
    diffeo_step<true ><<<NWG, threads, 0, stream>>>(B, A);  // s7 -> d_out
}